// Round 2
// baseline (1549.618 us; speedup 1.0000x reference)
//
#include <hip/hip_runtime.h>

typedef __bf16 bf16_t;
typedef bf16_t bf16x8 __attribute__((ext_vector_type(8)));
typedef float f32x4 __attribute__((ext_vector_type(4)));
typedef unsigned short u16x4 __attribute__((ext_vector_type(4)));
typedef unsigned short u16x8 __attribute__((ext_vector_type(8)));
typedef float f32x4v __attribute__((ext_vector_type(4)));

#define NL 4

__device__ __forceinline__ float bf2f(unsigned short u){
  unsigned int x = ((unsigned int)u) << 16;
  return __builtin_bit_cast(float, x);
}
__device__ __forceinline__ unsigned short f2bf(float f){
  unsigned int u = __builtin_bit_cast(unsigned int, f);
  u += 0x7FFFu + ((u >> 16) & 1u);
  return (unsigned short)(u >> 16);
}
__device__ __forceinline__ void gload16(const void* g, void* l){
  __builtin_amdgcn_global_load_lds((const __attribute__((address_space(1))) unsigned int*)g,
                                   (__attribute__((address_space(3))) unsigned int*)l, 16, 0, 0);
}
__device__ __forceinline__ float gelu_f(float x){
  float u = 0.7978845608028654f * (x + 0.044715f * x * x * x);
  return 0.5f * x * (1.0f + tanhf(u));
}

// ------- fused f32->bf16 convert + 64x64 transpose: dst[C x R](bf16) = src[R x C](f32)^T ----
__global__ __launch_bounds__(256) void transpose_cvt(const float* __restrict__ src,
                                                     unsigned short* __restrict__ dst,
                                                     int R, int C){
  __shared__ unsigned short tile[64][72];
  size_t boff = (size_t)blockIdx.z * (size_t)R * (size_t)C;
  int tc0 = blockIdx.x * 64, tr0 = blockIdx.y * 64;
  int t = threadIdx.x;
  int r = t >> 2, cs = (t & 3) * 16;
  const float* s = src + boff + (size_t)(tr0 + r) * C + tc0 + cs;
  #pragma unroll
  for (int j = 0; j < 16; j += 4){
    f32x4v v = *(const f32x4v*)(s + j);
    #pragma unroll
    for (int q = 0; q < 4; q++) tile[r][cs + j + q] = f2bf(v[q]);
  }
  __syncthreads();
  int n = t >> 2;
  unsigned short* d = dst + boff + (size_t)(tc0 + n) * R + tr0 + cs;
  u16x8 o0, o1;
  #pragma unroll
  for (int j = 0; j < 8; j++){ o0[j] = tile[cs + j][n]; o1[j] = tile[cs + 8 + j][n]; }
  *(u16x8*)d       = o0;
  *(u16x8*)(d + 8) = o1;
}

// ------- bf16 64x64 transpose (for V per layer) --------------------------------------
__global__ __launch_bounds__(256) void transpose64(const unsigned short* __restrict__ src,
                                                   unsigned short* __restrict__ dst,
                                                   int R, int C){
  __shared__ unsigned short tile[64][72];
  size_t boff = (size_t)blockIdx.z * (size_t)R * (size_t)C;
  int tc0 = blockIdx.x * 64, tr0 = blockIdx.y * 64;
  int t = threadIdx.x;
  int r = t >> 2, cs = (t & 3) * 16;
  const unsigned short* s = src + boff + (size_t)(tr0 + r) * C + tc0 + cs;
  *(u16x8*)(&tile[r][cs])     = *(const u16x8*)(s);
  *(u16x8*)(&tile[r][cs + 8]) = *(const u16x8*)(s + 8);
  __syncthreads();
  int n = t >> 2;
  unsigned short* d = dst + boff + (size_t)(tc0 + n) * R + tr0 + cs;
  u16x8 o0, o1;
  #pragma unroll
  for (int j = 0; j < 8; j++){ o0[j] = tile[cs + j][n]; o1[j] = tile[cs + 8 + j][n]; }
  *(u16x8*)d       = o0;
  *(u16x8*)(d + 8) = o1;
}

// ------- GEMM: C[M x N](bf16) = A[M x K](bf16) * BT[N x K](bf16)^T + bias(f32), opt GELU ----
template<int ACT>
__device__ __forceinline__ void gemm_core(const unsigned short* __restrict__ A,
                                          const unsigned short* __restrict__ BT,
                                          const float* __restrict__ bias,
                                          unsigned short* __restrict__ C,
                                          int m0, int n0, int N, int K){
  __shared__ unsigned short As[128 * 32];
  __shared__ unsigned short Bs[128 * 32];
  const int t = threadIdx.x;
  const int lane = t & 63;
  const int l15 = lane & 15, l4 = lane >> 4;
  const int w = t >> 6, wm = w >> 1, wn = w & 1;
  f32x4 acc[4][4] = {};
  const int rowA = t >> 2;
  const int segA = (t & 3) * 8;
  const unsigned short* Abase = A  + (size_t)(m0 + rowA) * K + segA;
  const unsigned short* Bbase = BT + (size_t)(n0 + rowA) * K + segA;
  for (int k0 = 0; k0 < K; k0 += 32){
    gload16(Abase + k0,                   As + t * 8);
    gload16(Abase + (size_t)64 * K + k0,  As + 2048 + t * 8);
    gload16(Bbase + k0,                   Bs + t * 8);
    gload16(Bbase + (size_t)64 * K + k0,  Bs + 2048 + t * 8);
    __syncthreads();
    bf16x8 af[4], bfr[4];
    #pragma unroll
    for (int i = 0; i < 4; i++){
      af[i]  = *(const bf16x8*)(As + (wm * 64 + i * 16 + l15) * 32 + l4 * 8);
      bfr[i] = *(const bf16x8*)(Bs + (wn * 64 + i * 16 + l15) * 32 + l4 * 8);
    }
    #pragma unroll
    for (int i = 0; i < 4; i++)
      #pragma unroll
      for (int j = 0; j < 4; j++)
        acc[i][j] = __builtin_amdgcn_mfma_f32_16x16x32_bf16(af[i], bfr[j], acc[i][j], 0, 0, 0);
    __syncthreads();
  }
  const int ccol0 = n0 + wn * 64 + l15;
  const int crow0 = m0 + wm * 64 + l4 * 4;
  #pragma unroll
  for (int j = 0; j < 4; j++){
    float bb = bias[ccol0 + j * 16];
    #pragma unroll
    for (int i = 0; i < 4; i++){
      #pragma unroll
      for (int r = 0; r < 4; r++){
        float v = acc[i][j][r] + bb;
        if (ACT == 1) v = gelu_f(v);
        C[(size_t)(crow0 + i * 16 + r) * N + ccol0 + j * 16] = f2bf(v);
      }
    }
  }
}

template<int ACT>
__global__ __launch_bounds__(256) void gemm_bt(const unsigned short* __restrict__ A,
                                               const unsigned short* __restrict__ BT,
                                               const float* __restrict__ bias,
                                               unsigned short* __restrict__ C, int N, int K){
  gemm_core<ACT>(A, BT, bias, C, blockIdx.x * 128, blockIdx.y * 128, N, K);
}

// fused Q/K/V projection: blockIdx.y selects {q,k,v} x 6 column tiles
__global__ __launch_bounds__(256) void qkv_gemm(const unsigned short* __restrict__ A,
                                                const unsigned short* __restrict__ wT,
                                                int l,
                                                const float* __restrict__ bq,
                                                const float* __restrict__ bk,
                                                const float* __restrict__ bv,
                                                unsigned short* __restrict__ q,
                                                unsigned short* __restrict__ k,
                                                unsigned short* __restrict__ v){
  int sel = blockIdx.y / 6;
  int n0 = (blockIdx.y % 6) * 128;
  const unsigned short* BT = wT + ((size_t)sel * NL + l) * (size_t)(768 * 768);
  const float* bias = sel == 0 ? bq : (sel == 1 ? bk : bv);
  unsigned short* C = sel == 0 ? q : (sel == 1 ? k : v);
  gemm_core<0>(A, BT, bias, C, blockIdx.x * 128, n0, 768, 768);
}

// ---------------- sliding-window attention -------------------------------------------
// grid (16 qblocks, 12 heads, 2 seqs), 256 threads = 4 waves x 64 queries
__global__ __launch_bounds__(256) void attn_kernel(const unsigned short* __restrict__ Q,
                                                   const unsigned short* __restrict__ Km,
                                                   const unsigned short* __restrict__ VT,
                                                   const int* __restrict__ mask1,
                                                   const int* __restrict__ mask2,
                                                   unsigned short* __restrict__ O){
  const int qb = blockIdx.x, h = blockIdx.y, seq = blockIdx.z;
  const int t = threadIdx.x, lane = t & 63, w = t >> 6;
  const int l15 = lane & 15, l4 = lane >> 4;
  __shared__ unsigned short Kc[64 * 64];
  __shared__ unsigned short VTc[64 * 64];
  __shared__ unsigned short Ps[4][16 * 64];
  const unsigned short* Qp  = Q  + (size_t)seq * 4096 * 768;
  const unsigned short* Kp  = Km + (size_t)seq * 4096 * 768;
  const unsigned short* VTp = VT + (size_t)seq * 768 * 4096;
  const int* mask = seq ? mask2 : mask1;
  unsigned short* Op = O + (size_t)seq * 4096 * 768;

  const int qrow0 = qb * 256 + w * 64;
  bf16x8 qa[4][2];
  #pragma unroll
  for (int m = 0; m < 4; m++)
    #pragma unroll
    for (int ks = 0; ks < 2; ks++)
      qa[m][ks] = *(const bf16x8*)(Qp + (size_t)(qrow0 + m * 16 + l15) * 768 + h * 64 + ks * 32 + l4 * 8);

  f32x4 oacc[4][4] = {};
  f32x4 rm[4], rl[4];
  #pragma unroll
  for (int m = 0; m < 4; m++)
    #pragma unroll
    for (int r = 0; r < 4; r++){ rm[m][r] = -1e30f; rl[m][r] = 0.0f; }

  const int kstart = (qb == 0) ? 0 : qb * 256 - 256;
  const int kend   = (qb == 15) ? 4096 : qb * 256 + 512;
  unsigned short* psw = &Ps[w][0];

  for (int kb = kstart; kb < kend; kb += 64){
    {
      int rr = t >> 3;
      int cc = (t & 7) * 8;
      gload16(Kp  + (size_t)(kb + rr) * 768 + h * 64 + cc,        Kc + t * 8);
      gload16(Kp  + (size_t)(kb + 32 + rr) * 768 + h * 64 + cc,   Kc + 2048 + t * 8);
      gload16(VTp + (size_t)(h * 64 + rr) * 4096 + kb + cc,       VTc + t * 8);
      gload16(VTp + (size_t)(h * 64 + 32 + rr) * 4096 + kb + cc,  VTc + 2048 + t * 8);
    }
    __syncthreads();
    bool active = (kb + 63 >= qrow0 - 256) && (kb <= qrow0 + 63 + 256);
    if (active){
      bool mv[4]; int kcol[4];
      #pragma unroll
      for (int n = 0; n < 4; n++){ kcol[n] = kb + n * 16 + l15; mv[n] = (mask[kcol[n]] != 0); }
      bf16x8 vb[4][2];
      #pragma unroll
      for (int g = 0; g < 4; g++)
        #pragma unroll
        for (int ks = 0; ks < 2; ks++)
          vb[g][ks] = *(const bf16x8*)(VTc + (g * 16 + l15) * 64 + ks * 32 + l4 * 8);

      #pragma unroll
      for (int m = 0; m < 4; m++){
        f32x4 s[4];
        #pragma unroll
        for (int n = 0; n < 4; n++){
          bf16x8 kf0 = *(const bf16x8*)(Kc + (n * 16 + l15) * 64 + l4 * 8);
          bf16x8 kf1 = *(const bf16x8*)(Kc + (n * 16 + l15) * 64 + 32 + l4 * 8);
          f32x4 z = {};
          z    = __builtin_amdgcn_mfma_f32_16x16x32_bf16(qa[m][0], kf0, z, 0, 0, 0);
          s[n] = __builtin_amdgcn_mfma_f32_16x16x32_bf16(qa[m][1], kf1, z, 0, 0, 0);
        }
        const int qposb = qrow0 + m * 16 + l4 * 4;
        #pragma unroll
        for (int n = 0; n < 4; n++)
          #pragma unroll
          for (int r = 0; r < 4; r++){
            float v = s[n][r] * 0.125f;
            int d = kcol[n] - (qposb + r);
            bool ok = mv[n] && (d <= 256) && (d >= -256);
            s[n][r] = ok ? v : -1e30f;
          }
        f32x4 cm;
        #pragma unroll
        for (int r = 0; r < 4; r++) cm[r] = fmaxf(fmaxf(s[0][r], s[1][r]), fmaxf(s[2][r], s[3][r]));
        #pragma unroll
        for (int off = 1; off < 16; off <<= 1)
          #pragma unroll
          for (int r = 0; r < 4; r++) cm[r] = fmaxf(cm[r], __shfl_xor(cm[r], off, 64));
        f32x4 sc;
        #pragma unroll
        for (int r = 0; r < 4; r++){
          float nm = fmaxf(rm[m][r], cm[r]);
          sc[r] = __expf(rm[m][r] - nm);
          rm[m][r] = nm;
        }
        f32x4 rs;
        #pragma unroll
        for (int r = 0; r < 4; r++) rs[r] = 0.0f;
        #pragma unroll
        for (int n = 0; n < 4; n++)
          #pragma unroll
          for (int r = 0; r < 4; r++){
            float p = (s[n][r] > -1e29f) ? __expf(s[n][r] - rm[m][r]) : 0.0f;
            s[n][r] = p;
            rs[r] += p;
          }
        #pragma unroll
        for (int off = 1; off < 16; off <<= 1)
          #pragma unroll
          for (int r = 0; r < 4; r++) rs[r] += __shfl_xor(rs[r], off, 64);
        #pragma unroll
        for (int r = 0; r < 4; r++) rl[m][r] = rl[m][r] * sc[r] + rs[r];
        #pragma unroll
        for (int g = 0; g < 4; g++)
          #pragma unroll
          for (int r = 0; r < 4; r++) oacc[m][g][r] *= sc[r];
        // P -> LDS (relayout for A-operand), then PV
        #pragma unroll
        for (int n = 0; n < 4; n++)
          #pragma unroll
          for (int r = 0; r < 4; r++)
            psw[(l4 * 4 + r) * 64 + n * 16 + l15] = f2bf(s[n][r]);
        asm volatile("s_waitcnt lgkmcnt(0)" ::: "memory");
        __builtin_amdgcn_sched_barrier(0);
        bf16x8 pa0 = *(const bf16x8*)(psw + l15 * 64 + l4 * 8);
        bf16x8 pa1 = *(const bf16x8*)(psw + l15 * 64 + 32 + l4 * 8);
        #pragma unroll
        for (int g = 0; g < 4; g++){
          oacc[m][g] = __builtin_amdgcn_mfma_f32_16x16x32_bf16(pa0, vb[g][0], oacc[m][g], 0, 0, 0);
          oacc[m][g] = __builtin_amdgcn_mfma_f32_16x16x32_bf16(pa1, vb[g][1], oacc[m][g], 0, 0, 0);
        }
      }
    }
    __syncthreads();
  }
  #pragma unroll
  for (int m = 0; m < 4; m++)
    #pragma unroll
    for (int g = 0; g < 4; g++)
      #pragma unroll
      for (int r = 0; r < 4; r++){
        float v = oacc[m][g][r] / rl[m][r];
        Op[(size_t)(qrow0 + m * 16 + l4 * 4 + r) * 768 + h * 64 + g * 16 + l15] = f2bf(v);
      }
}

// ---------------- embed + LN (f32 tables -> bf16 out) --------------------------------
__global__ __launch_bounds__(192) void embed_ln(const int* __restrict__ ids1,
                                                const int* __restrict__ ids2,
                                                const float* __restrict__ we,
                                                const float* __restrict__ pe,
                                                const float* __restrict__ g,
                                                const float* __restrict__ b,
                                                unsigned short* __restrict__ out){
  const int row = blockIdx.x;
  const int seq = row >> 12, s = row & 4095;
  const int t = threadIdx.x;
  const int id = (seq ? ids2 : ids1)[s];
  f32x4v wvv = *(const f32x4v*)(we + (size_t)id * 768 + t * 4);
  f32x4v pv  = *(const f32x4v*)(pe + (size_t)s * 768 + t * 4);
  float v[4];
  #pragma unroll
  for (int j = 0; j < 4; j++) v[j] = wvv[j] + pv[j];
  float sum = 0, ss = 0;
  #pragma unroll
  for (int j = 0; j < 4; j++){ sum += v[j]; ss += v[j] * v[j]; }
  for (int off = 1; off < 64; off <<= 1){ sum += __shfl_xor(sum, off, 64); ss += __shfl_xor(ss, off, 64); }
  __shared__ float red[2][3];
  int wid = t >> 6;
  if ((t & 63) == 0){ red[0][wid] = sum; red[1][wid] = ss; }
  __syncthreads();
  sum = red[0][0] + red[0][1] + red[0][2];
  ss  = red[1][0] + red[1][1] + red[1][2];
  float mean = sum * (1.0f / 768.0f);
  float var  = ss * (1.0f / 768.0f) - mean * mean;
  float rstd = rsqrtf(var + 1e-5f);
  f32x4v gv = *(const f32x4v*)(g + t * 4);
  f32x4v bv = *(const f32x4v*)(b + t * 4);
  u16x4 o;
  #pragma unroll
  for (int j = 0; j < 4; j++) o[j] = f2bf((v[j] - mean) * rstd * gv[j] + bv[j]);
  *(u16x4*)(out + (size_t)row * 768 + t * 4) = o;
}

// ---------------- (A + B) -> LayerNorm -----------------------------------------------
__global__ __launch_bounds__(192) void add_ln(const unsigned short* __restrict__ A,
                                              const unsigned short* __restrict__ Bp,
                                              const float* __restrict__ g,
                                              const float* __restrict__ b,
                                              unsigned short* __restrict__ out){
  const int row = blockIdx.x;
  const int t = threadIdx.x;
  u16x4 a4 = *(const u16x4*)(A  + (size_t)row * 768 + t * 4);
  u16x4 b4 = *(const u16x4*)(Bp + (size_t)row * 768 + t * 4);
  float v[4];
  #pragma unroll
  for (int j = 0; j < 4; j++) v[j] = bf2f(a4[j]) + bf2f(b4[j]);
  float sum = 0, ss = 0;
  #pragma unroll
  for (int j = 0; j < 4; j++){ sum += v[j]; ss += v[j] * v[j]; }
  for (int off = 1; off < 64; off <<= 1){ sum += __shfl_xor(sum, off, 64); ss += __shfl_xor(ss, off, 64); }
  __shared__ float red[2][3];
  int wid = t >> 6;
  if ((t & 63) == 0){ red[0][wid] = sum; red[1][wid] = ss; }
  __syncthreads();
  sum = red[0][0] + red[0][1] + red[0][2];
  ss  = red[1][0] + red[1][1] + red[1][2];
  float mean = sum * (1.0f / 768.0f);
  float var  = ss * (1.0f / 768.0f) - mean * mean;
  float rstd = rsqrtf(var + 1e-5f);
  f32x4v gv = *(const f32x4v*)(g + t * 4);
  f32x4v bv = *(const f32x4v*)(b + t * 4);
  u16x4 o;
  #pragma unroll
  for (int j = 0; j < 4; j++) o[j] = f2bf((v[j] - mean) * rstd * gv[j] + bv[j]);
  *(u16x4*)(out + (size_t)row * 768 + t * 4) = o;
}

// ---------------- column sums ---------------------------------------------------------
__global__ __launch_bounds__(256) void colmean(const unsigned short* __restrict__ X,
                                               float* __restrict__ mean){
  const int t = threadIdx.x;
  const int seq = blockIdx.y;
  const int r0 = blockIdx.x * 64;
  const unsigned short* base = X + ((size_t)seq * 4096 + r0) * 768;
  float a0 = 0, a1 = 0, a2 = 0;
  for (int r = 0; r < 64; r++){
    const unsigned short* p = base + (size_t)r * 768;
    a0 += bf2f(p[t]);
    a1 += bf2f(p[t + 256]);
    a2 += bf2f(p[t + 512]);
  }
  atomicAdd(&mean[seq * 768 + t], a0);
  atomicAdd(&mean[seq * 768 + t + 256], a1);
  atomicAdd(&mean[seq * 768 + t + 512], a2);
}

// ---------------- final dot + sigmoid (f32 out) ---------------------------------------
__global__ __launch_bounds__(256) void final_k(const float* __restrict__ means,
                                               const float* __restrict__ dw,
                                               const float* __restrict__ db,
                                               float* __restrict__ out){
  const int t = threadIdx.x;
  float part = 0;
  for (int c = t; c < 768; c += 256)
    part += (means[c] - means[768 + c]) * (1.0f / 4096.0f) * dw[c];
  for (int off = 1; off < 64; off <<= 1) part += __shfl_xor(part, off, 64);
  __shared__ float red[4];
  if ((t & 63) == 0) red[t >> 6] = part;
  __syncthreads();
  if (t == 0){
    float r = red[0] + red[1] + red[2] + red[3] + db[0];
    out[0] = 1.0f / (1.0f + expf(-r));
  }
}

// sentinel: written when workspace is too small, to make that failure diagnosable
__global__ void sentinel_k(float* out){ out[0] = -1.0f; }

extern "C" void kernel_launch(void* const* d_in, const int* in_sizes, int n_in,
                              void* d_out, int out_size, void* d_ws, size_t ws_size,
                              hipStream_t stream){
  (void)in_sizes; (void)n_in; (void)out_size;
  const int* ids1  = (const int*)d_in[0];
  const int* ids2  = (const int*)d_in[1];
  const int* mask1 = (const int*)d_in[2];
  const int* mask2 = (const int*)d_in[3];
  const float* we = (const float*)d_in[4];
  const float* pe = (const float*)d_in[5];
  const float* eg = (const float*)d_in[6];
  const float* eb = (const float*)d_in[7];
  const float* wq = (const float*)d_in[8];
  const float* bq = (const float*)d_in[9];
  const float* wk = (const float*)d_in[10];
  const float* bk = (const float*)d_in[11];
  const float* wv = (const float*)d_in[12];
  const float* bv = (const float*)d_in[13];
  const float* wo = (const float*)d_in[14];
  const float* bo = (const float*)d_in[15];
  const float* g1 = (const float*)d_in[16];
  const float* b1 = (const float*)d_in[17];
  const float* w1 = (const float*)d_in[18];
  const float* c1 = (const float*)d_in[19];
  const float* w2 = (const float*)d_in[20];
  const float* c2 = (const float*)d_in[21];
  const float* g2 = (const float*)d_in[22];
  const float* b2 = (const float*)d_in[23];
  const float* dw = (const float*)d_in[24];
  const float* db = (const float*)d_in[25];
  float* outp = (float*)d_out;

  char* ws = (char*)d_ws;
  size_t off = 0;
  auto alloc = [&](size_t bytes) -> char* {
    char* p = ws + off;
    off += (bytes + 255) & ~(size_t)255;
    return p;
  };
  const size_t W768 = (size_t)768 * 768;
  const size_t WFF  = (size_t)768 * 3072;
  unsigned short* wqkvT = (unsigned short*)alloc(3 * NL * W768 * 2);
  unsigned short* woT   = (unsigned short*)alloc(NL * W768 * 2);
  unsigned short* w1T   = (unsigned short*)alloc(NL * WFF * 2);
  unsigned short* w2T   = (unsigned short*)alloc(NL * WFF * 2);
  unsigned short* xb    = (unsigned short*)alloc((size_t)8192 * 768 * 2);
  unsigned short* qb_   = (unsigned short*)alloc((size_t)8192 * 768 * 2);
  unsigned short* kb_   = (unsigned short*)alloc((size_t)8192 * 768 * 2);
  unsigned short* vb_   = (unsigned short*)alloc((size_t)8192 * 768 * 2);
  unsigned short* hb    = (unsigned short*)alloc((size_t)8192 * 3072 * 2);
  unsigned short* vt    = (unsigned short*)alloc((size_t)2 * 768 * 4096 * 2);
  float* means          = (float*)alloc(2 * 768 * 4);
  if (off > ws_size){ sentinel_k<<<1, 1, 0, stream>>>(outp); return; }

  // one-time (per call) weight convert+transpose to bf16 B^T layout
  transpose_cvt<<<dim3(12, 12, NL), 256, 0, stream>>>(wq, wqkvT,                 768, 768);
  transpose_cvt<<<dim3(12, 12, NL), 256, 0, stream>>>(wk, wqkvT + NL * W768,     768, 768);
  transpose_cvt<<<dim3(12, 12, NL), 256, 0, stream>>>(wv, wqkvT + 2 * NL * W768, 768, 768);
  transpose_cvt<<<dim3(12, 12, NL), 256, 0, stream>>>(wo, woT,                   768, 768);
  transpose_cvt<<<dim3(48, 12, NL), 256, 0, stream>>>(w1, w1T,                   768, 3072);
  transpose_cvt<<<dim3(12, 48, NL), 256, 0, stream>>>(w2, w2T,                   3072, 768);

  embed_ln<<<8192, 192, 0, stream>>>(ids1, ids2, we, pe, eg, eb, xb);

  for (int l = 0; l < NL; l++){
    qkv_gemm<<<dim3(64, 18), 256, 0, stream>>>(xb, wqkvT, l, bq + l * 768, bk + l * 768, bv + l * 768,
                                               qb_, kb_, vb_);
    transpose64<<<dim3(12, 64, 2), 256, 0, stream>>>(vb_, vt, 4096, 768);
    attn_kernel<<<dim3(16, 12, 2), 256, 0, stream>>>(qb_, kb_, vt, mask1, mask2, vb_);
    gemm_bt<0><<<dim3(64, 6), 256, 0, stream>>>(vb_, woT + (size_t)l * W768, bo + l * 768, qb_, 768, 768);
    add_ln<<<8192, 192, 0, stream>>>(xb, qb_, g1 + l * 768, b1 + l * 768, kb_);
    gemm_bt<1><<<dim3(64, 24), 256, 0, stream>>>(kb_, w1T + (size_t)l * WFF, c1 + l * 3072, hb, 3072, 768);
    gemm_bt<0><<<dim3(64, 6), 256, 0, stream>>>(hb, w2T + (size_t)l * WFF, c2 + l * 768, vb_, 768, 3072);
    add_ln<<<8192, 192, 0, stream>>>(kb_, vb_, g2 + l * 768, b2 + l * 768, xb);
  }

  hipMemsetAsync(means, 0, 2 * 768 * 4, stream);
  colmean<<<dim3(64, 2), 256, 0, stream>>>(xb, means);
  final_k<<<1, 256, 0, stream>>>(means, dw, db, outp);
}

// Round 3
// 1235.022 us; speedup vs baseline: 1.2547x; 1.2547x over previous
//
#include <hip/hip_runtime.h>

typedef __bf16 bf16_t;
typedef bf16_t bf16x8 __attribute__((ext_vector_type(8)));
typedef float f32x4 __attribute__((ext_vector_type(4)));
typedef unsigned short u16x4 __attribute__((ext_vector_type(4)));
typedef unsigned short u16x8 __attribute__((ext_vector_type(8)));
typedef float f32x4v __attribute__((ext_vector_type(4)));

#define NL 4

__device__ __forceinline__ float bf2f(unsigned short u){
  unsigned int x = ((unsigned int)u) << 16;
  return __builtin_bit_cast(float, x);
}
__device__ __forceinline__ unsigned short f2bf(float f){
  unsigned int u = __builtin_bit_cast(unsigned int, f);
  u += 0x7FFFu + ((u >> 16) & 1u);
  return (unsigned short)(u >> 16);
}
__device__ __forceinline__ void gload16(const void* g, void* l){
  __builtin_amdgcn_global_load_lds((const __attribute__((address_space(1))) unsigned int*)g,
                                   (__attribute__((address_space(3))) unsigned int*)l, 16, 0, 0);
}
__device__ __forceinline__ float gelu_f(float x){
  float u = 0.7978845608028654f * (x + 0.044715f * x * x * x);
  return 0.5f * x * (1.0f + tanhf(u));
}

// ------- fused f32->bf16 convert + 64x64 transpose: dst[C x R](bf16) = src[R x C](f32)^T ----
__global__ __launch_bounds__(256) void transpose_cvt(const float* __restrict__ src,
                                                     unsigned short* __restrict__ dst,
                                                     int R, int C){
  __shared__ unsigned short tile[64][72];
  size_t boff = (size_t)blockIdx.z * (size_t)R * (size_t)C;
  int tc0 = blockIdx.x * 64, tr0 = blockIdx.y * 64;
  int t = threadIdx.x;
  int r = t >> 2, cs = (t & 3) * 16;
  const float* s = src + boff + (size_t)(tr0 + r) * C + tc0 + cs;
  #pragma unroll
  for (int j = 0; j < 16; j += 4){
    f32x4v v = *(const f32x4v*)(s + j);
    #pragma unroll
    for (int q = 0; q < 4; q++) tile[r][cs + j + q] = f2bf(v[q]);
  }
  __syncthreads();
  int n = t >> 2;
  unsigned short* d = dst + boff + (size_t)(tc0 + n) * R + tr0 + cs;
  u16x8 o0, o1;
  #pragma unroll
  for (int j = 0; j < 8; j++){ o0[j] = tile[cs + j][n]; o1[j] = tile[cs + 8 + j][n]; }
  *(u16x8*)d       = o0;
  *(u16x8*)(d + 8) = o1;
}

// ------- bf16 64x64 transpose (for V per layer) --------------------------------------
__global__ __launch_bounds__(256) void transpose64(const unsigned short* __restrict__ src,
                                                   unsigned short* __restrict__ dst,
                                                   int R, int C){
  __shared__ unsigned short tile[64][72];
  size_t boff = (size_t)blockIdx.z * (size_t)R * (size_t)C;
  int tc0 = blockIdx.x * 64, tr0 = blockIdx.y * 64;
  int t = threadIdx.x;
  int r = t >> 2, cs = (t & 3) * 16;
  const unsigned short* s = src + boff + (size_t)(tr0 + r) * C + tc0 + cs;
  *(u16x8*)(&tile[r][cs])     = *(const u16x8*)(s);
  *(u16x8*)(&tile[r][cs + 8]) = *(const u16x8*)(s + 8);
  __syncthreads();
  int n = t >> 2;
  unsigned short* d = dst + boff + (size_t)(tc0 + n) * R + tr0 + cs;
  u16x8 o0, o1;
  #pragma unroll
  for (int j = 0; j < 8; j++){ o0[j] = tile[cs + j][n]; o1[j] = tile[cs + 8 + j][n]; }
  *(u16x8*)d       = o0;
  *(u16x8*)(d + 8) = o1;
}

// ------- GEMM: C[M x N](bf16) = A[M x K](bf16) * BT[N x K](bf16)^T + bias(f32), opt GELU ----
template<int ACT>
__device__ __forceinline__ void gemm_core(const unsigned short* __restrict__ A,
                                          const unsigned short* __restrict__ BT,
                                          const float* __restrict__ bias,
                                          unsigned short* __restrict__ C,
                                          int m0, int n0, int N, int K){
  __shared__ unsigned short As[128 * 32];
  __shared__ unsigned short Bs[128 * 32];
  const int t = threadIdx.x;
  const int lane = t & 63;
  const int l15 = lane & 15, l4 = lane >> 4;
  const int w = t >> 6, wm = w >> 1, wn = w & 1;
  f32x4 acc[4][4] = {};
  const int rowA = t >> 2;
  const int segA = (t & 3) * 8;
  const unsigned short* Abase = A  + (size_t)(m0 + rowA) * K + segA;
  const unsigned short* Bbase = BT + (size_t)(n0 + rowA) * K + segA;
  for (int k0 = 0; k0 < K; k0 += 32){
    gload16(Abase + k0,                   As + t * 8);
    gload16(Abase + (size_t)64 * K + k0,  As + 2048 + t * 8);
    gload16(Bbase + k0,                   Bs + t * 8);
    gload16(Bbase + (size_t)64 * K + k0,  Bs + 2048 + t * 8);
    __syncthreads();
    bf16x8 af[4], bfr[4];
    #pragma unroll
    for (int i = 0; i < 4; i++){
      af[i]  = *(const bf16x8*)(As + (wm * 64 + i * 16 + l15) * 32 + l4 * 8);
      bfr[i] = *(const bf16x8*)(Bs + (wn * 64 + i * 16 + l15) * 32 + l4 * 8);
    }
    #pragma unroll
    for (int i = 0; i < 4; i++)
      #pragma unroll
      for (int j = 0; j < 4; j++)
        acc[i][j] = __builtin_amdgcn_mfma_f32_16x16x32_bf16(af[i], bfr[j], acc[i][j], 0, 0, 0);
    __syncthreads();
  }
  const int ccol0 = n0 + wn * 64 + l15;
  const int crow0 = m0 + wm * 64 + l4 * 4;
  #pragma unroll
  for (int j = 0; j < 4; j++){
    float bb = bias[ccol0 + j * 16];
    #pragma unroll
    for (int i = 0; i < 4; i++){
      #pragma unroll
      for (int r = 0; r < 4; r++){
        float v = acc[i][j][r] + bb;
        if (ACT == 1) v = gelu_f(v);
        C[(size_t)(crow0 + i * 16 + r) * N + ccol0 + j * 16] = f2bf(v);
      }
    }
  }
}

template<int ACT>
__global__ __launch_bounds__(256) void gemm_bt(const unsigned short* __restrict__ A,
                                               const unsigned short* __restrict__ BT,
                                               const float* __restrict__ bias,
                                               unsigned short* __restrict__ C, int N, int K){
  gemm_core<ACT>(A, BT, bias, C, blockIdx.x * 128, blockIdx.y * 128, N, K);
}

// fused Q/K/V projection: blockIdx.y selects {q,k,v} x 6 column tiles
__global__ __launch_bounds__(256) void qkv_gemm(const unsigned short* __restrict__ A,
                                                const unsigned short* __restrict__ wT,
                                                int l,
                                                const float* __restrict__ bq,
                                                const float* __restrict__ bk,
                                                const float* __restrict__ bv,
                                                unsigned short* __restrict__ q,
                                                unsigned short* __restrict__ k,
                                                unsigned short* __restrict__ v){
  int sel = blockIdx.y / 6;
  int n0 = (blockIdx.y % 6) * 128;
  const unsigned short* BT = wT + ((size_t)sel * NL + l) * (size_t)(768 * 768);
  const float* bias = sel == 0 ? bq : (sel == 1 ? bk : bv);
  unsigned short* C = sel == 0 ? q : (sel == 1 ? k : v);
  gemm_core<0>(A, BT, bias, C, blockIdx.x * 128, n0, 768, 768);
}

// ---------------- sliding-window attention (swapped-QK, swizzled LDS) -----------------
// grid (64 qtiles, 12 heads, 2 seqs), 256 threads = 4 waves x 16 queries each.
// S^T = mfma(K, Q): lane's softmax query = lane&15; C-rows = keys.
// LDS tiles swizzled: elem_off_in_row ^= (row&7)*8  (16B-slot XOR, T2/rule21:
// linear gload_lds dest + inverse-swizzled GLOBAL source + swizzled reads).
__global__ __launch_bounds__(256, 4) void attn_kernel(const unsigned short* __restrict__ Q,
                                                      const unsigned short* __restrict__ Km,
                                                      const unsigned short* __restrict__ VT,
                                                      const int* __restrict__ mask1,
                                                      const int* __restrict__ mask2,
                                                      unsigned short* __restrict__ O){
  const int qt = blockIdx.x, h = blockIdx.y, seq = blockIdx.z;
  const int t = threadIdx.x, lane = t & 63, w = t >> 6;
  const int l15 = lane & 15, l4 = lane >> 4;
  __shared__ unsigned short Kc[64 * 64];   // [key][d], swizzled
  __shared__ unsigned short VTc[64 * 64];  // [d][key], swizzled
  __shared__ unsigned short Ps[4][16 * 64];// per-wave P[q][key], swizzled
  const unsigned short* Qp  = Q  + (size_t)seq * 4096 * 768;
  const unsigned short* Kp  = Km + (size_t)seq * 4096 * 768;
  const unsigned short* VTp = VT + (size_t)seq * 768 * 4096;
  const int* mask = seq ? mask2 : mask1;
  unsigned short* Op = O + (size_t)seq * 4096 * 768;

  const int q0 = qt * 64 + w * 16;   // wave's first query
  const int qg = q0 + l15;           // this lane's softmax query
  const int swz = (l15 & 7) * 8;     // read-side swizzle (row = l15-derived for all reads)

  // Q as B-fragment: lane holds Q[q0+l15][d = ks*32 + l4*8 .. +7]
  bf16x8 qf[2];
  #pragma unroll
  for (int ks = 0; ks < 2; ks++)
    qf[ks] = *(const bf16x8*)(Qp + (size_t)qg * 768 + h * 64 + ks * 32 + l4 * 8);

  f32x4 oacc[4] = {};
  float rm = -1e30f, rl = 0.0f;

  const int kstart = qt * 64 >= 256 ? qt * 64 - 256 : 0;
  const int kend0  = qt * 64 + 320;
  const int kend   = kend0 > 4096 ? 4096 : kend0;
  unsigned short* psw = &Ps[w][0];

  // staging: slot t holds (row rr, 16B-slot c8/8) with inverse-swizzled source column
  const int rr = t >> 3;
  const int c8 = (((t & 7) ^ (rr & 7)) * 8);

  for (int kb = kstart; kb < kend; kb += 64){
    gload16(Kp  + (size_t)(kb + rr) * 768 + h * 64 + c8,       Kc + t * 8);
    gload16(Kp  + (size_t)(kb + 32 + rr) * 768 + h * 64 + c8,  Kc + 2048 + t * 8);
    gload16(VTp + (size_t)(h * 64 + rr) * 4096 + kb + c8,      VTc + t * 8);
    gload16(VTp + (size_t)(h * 64 + 32 + rr) * 4096 + kb + c8, VTc + 2048 + t * 8);
    __syncthreads();
    if (kb + 63 >= q0 - 256 && kb <= q0 + 271){
      // S^T[key][q] = K * Q^T
      f32x4 sT[4];
      #pragma unroll
      for (int mt = 0; mt < 4; mt++){
        const unsigned short* kr = Kc + (mt * 16 + l15) * 64;
        bf16x8 kf0 = *(const bf16x8*)(kr + ((l4 * 8) ^ swz));
        bf16x8 kf1 = *(const bf16x8*)(kr + ((32 + l4 * 8) ^ swz));
        f32x4 z = {};
        z      = __builtin_amdgcn_mfma_f32_16x16x32_bf16(kf0, qf[0], z, 0, 0, 0);
        sT[mt] = __builtin_amdgcn_mfma_f32_16x16x32_bf16(kf1, qf[1], z, 0, 0, 0);
      }
      // mask + band; lane's 16 scores all belong to query qg
      float smax = -1e30f;
      #pragma unroll
      for (int mt = 0; mt < 4; mt++){
        int4 mv = *(const int4*)(mask + kb + mt * 16 + l4 * 4);
        #pragma unroll
        for (int r = 0; r < 4; r++){
          int kgl = kb + mt * 16 + l4 * 4 + r;
          int d = kgl - qg;
          int mvv = (r == 0) ? mv.x : (r == 1) ? mv.y : (r == 2) ? mv.z : mv.w;
          bool ok = (mvv != 0) && (d <= 256) && (d >= -256);
          float v = sT[mt][r] * 0.125f;
          sT[mt][r] = ok ? v : -1e30f;
          smax = fmaxf(smax, sT[mt][r]);
        }
      }
      smax = fmaxf(smax, __shfl_xor(smax, 16, 64));
      smax = fmaxf(smax, __shfl_xor(smax, 32, 64));
      float nm = fmaxf(rm, smax);
      float sc = __expf(rm - nm);
      rm = nm;
      float psum = 0.0f;
      #pragma unroll
      for (int mt = 0; mt < 4; mt++){
        u16x4 pk;
        #pragma unroll
        for (int r = 0; r < 4; r++){
          float p = (sT[mt][r] > -1e29f) ? __expf(sT[mt][r] - nm) : 0.0f;
          psum += p;
          pk[r] = f2bf(p);
        }
        *(u16x4*)(psw + l15 * 64 + ((mt * 16 + l4 * 4) ^ swz)) = pk;
      }
      psum += __shfl_xor(psum, 16, 64);
      psum += __shfl_xor(psum, 32, 64);
      rl = rl * sc + psum;
      // rescale: C-rows of oacc are queries q0 + l4*4 + r -> gather their sc
      float scq[4];
      #pragma unroll
      for (int r = 0; r < 4; r++) scq[r] = __shfl(sc, l4 * 4 + r, 64);
      #pragma unroll
      for (int g = 0; g < 4; g++)
        #pragma unroll
        for (int r = 0; r < 4; r++) oacc[g][r] *= scq[r];
      asm volatile("s_waitcnt lgkmcnt(0)" ::: "memory");
      __builtin_amdgcn_sched_barrier(0);
      bf16x8 pa0 = *(const bf16x8*)(psw + l15 * 64 + ((l4 * 8) ^ swz));
      bf16x8 pa1 = *(const bf16x8*)(psw + l15 * 64 + ((32 + l4 * 8) ^ swz));
      #pragma unroll
      for (int g = 0; g < 4; g++){
        const unsigned short* vr = VTc + (g * 16 + l15) * 64;
        bf16x8 vb0 = *(const bf16x8*)(vr + ((l4 * 8) ^ swz));
        bf16x8 vb1 = *(const bf16x8*)(vr + ((32 + l4 * 8) ^ swz));
        oacc[g] = __builtin_amdgcn_mfma_f32_16x16x32_bf16(pa0, vb0, oacc[g], 0, 0, 0);
        oacc[g] = __builtin_amdgcn_mfma_f32_16x16x32_bf16(pa1, vb1, oacc[g], 0, 0, 0);
      }
    }
    __syncthreads();
  }
  float rlq[4];
  #pragma unroll
  for (int r = 0; r < 4; r++) rlq[r] = __shfl(rl, l4 * 4 + r, 64);
  #pragma unroll
  for (int g = 0; g < 4; g++)
    #pragma unroll
    for (int r = 0; r < 4; r++){
      float v = oacc[g][r] / rlq[r];
      Op[(size_t)(q0 + l4 * 4 + r) * 768 + h * 64 + g * 16 + l15] = f2bf(v);
    }
}

// ---------------- embed + LN (f32 tables -> bf16 out) --------------------------------
__global__ __launch_bounds__(192) void embed_ln(const int* __restrict__ ids1,
                                                const int* __restrict__ ids2,
                                                const float* __restrict__ we,
                                                const float* __restrict__ pe,
                                                const float* __restrict__ g,
                                                const float* __restrict__ b,
                                                unsigned short* __restrict__ out){
  const int row = blockIdx.x;
  const int seq = row >> 12, s = row & 4095;
  const int t = threadIdx.x;
  const int id = (seq ? ids2 : ids1)[s];
  f32x4v wvv = *(const f32x4v*)(we + (size_t)id * 768 + t * 4);
  f32x4v pv  = *(const f32x4v*)(pe + (size_t)s * 768 + t * 4);
  float v[4];
  #pragma unroll
  for (int j = 0; j < 4; j++) v[j] = wvv[j] + pv[j];
  float sum = 0, ss = 0;
  #pragma unroll
  for (int j = 0; j < 4; j++){ sum += v[j]; ss += v[j] * v[j]; }
  for (int off = 1; off < 64; off <<= 1){ sum += __shfl_xor(sum, off, 64); ss += __shfl_xor(ss, off, 64); }
  __shared__ float red[2][3];
  int wid = t >> 6;
  if ((t & 63) == 0){ red[0][wid] = sum; red[1][wid] = ss; }
  __syncthreads();
  sum = red[0][0] + red[0][1] + red[0][2];
  ss  = red[1][0] + red[1][1] + red[1][2];
  float mean = sum * (1.0f / 768.0f);
  float var  = ss * (1.0f / 768.0f) - mean * mean;
  float rstd = rsqrtf(var + 1e-5f);
  f32x4v gv = *(const f32x4v*)(g + t * 4);
  f32x4v bv = *(const f32x4v*)(b + t * 4);
  u16x4 o;
  #pragma unroll
  for (int j = 0; j < 4; j++) o[j] = f2bf((v[j] - mean) * rstd * gv[j] + bv[j]);
  *(u16x4*)(out + (size_t)row * 768 + t * 4) = o;
}

// ---------------- (A + B) -> LayerNorm -----------------------------------------------
__global__ __launch_bounds__(192) void add_ln(const unsigned short* __restrict__ A,
                                              const unsigned short* __restrict__ Bp,
                                              const float* __restrict__ g,
                                              const float* __restrict__ b,
                                              unsigned short* __restrict__ out){
  const int row = blockIdx.x;
  const int t = threadIdx.x;
  u16x4 a4 = *(const u16x4*)(A  + (size_t)row * 768 + t * 4);
  u16x4 b4 = *(const u16x4*)(Bp + (size_t)row * 768 + t * 4);
  float v[4];
  #pragma unroll
  for (int j = 0; j < 4; j++) v[j] = bf2f(a4[j]) + bf2f(b4[j]);
  float sum = 0, ss = 0;
  #pragma unroll
  for (int j = 0; j < 4; j++){ sum += v[j]; ss += v[j] * v[j]; }
  for (int off = 1; off < 64; off <<= 1){ sum += __shfl_xor(sum, off, 64); ss += __shfl_xor(ss, off, 64); }
  __shared__ float red[2][3];
  int wid = t >> 6;
  if ((t & 63) == 0){ red[0][wid] = sum; red[1][wid] = ss; }
  __syncthreads();
  sum = red[0][0] + red[0][1] + red[0][2];
  ss  = red[1][0] + red[1][1] + red[1][2];
  float mean = sum * (1.0f / 768.0f);
  float var  = ss * (1.0f / 768.0f) - mean * mean;
  float rstd = rsqrtf(var + 1e-5f);
  f32x4v gv = *(const f32x4v*)(g + t * 4);
  f32x4v bv = *(const f32x4v*)(b + t * 4);
  u16x4 o;
  #pragma unroll
  for (int j = 0; j < 4; j++) o[j] = f2bf((v[j] - mean) * rstd * gv[j] + bv[j]);
  *(u16x4*)(out + (size_t)row * 768 + t * 4) = o;
}

// ---------------- column sums ---------------------------------------------------------
__global__ __launch_bounds__(256) void colmean(const unsigned short* __restrict__ X,
                                               float* __restrict__ mean){
  const int t = threadIdx.x;
  const int seq = blockIdx.y;
  const int r0 = blockIdx.x * 64;
  const unsigned short* base = X + ((size_t)seq * 4096 + r0) * 768;
  float a0 = 0, a1 = 0, a2 = 0;
  for (int r = 0; r < 64; r++){
    const unsigned short* p = base + (size_t)r * 768;
    a0 += bf2f(p[t]);
    a1 += bf2f(p[t + 256]);
    a2 += bf2f(p[t + 512]);
  }
  atomicAdd(&mean[seq * 768 + t], a0);
  atomicAdd(&mean[seq * 768 + t + 256], a1);
  atomicAdd(&mean[seq * 768 + t + 512], a2);
}

// ---------------- final dot + sigmoid (f32 out) ---------------------------------------
__global__ __launch_bounds__(256) void final_k(const float* __restrict__ means,
                                               const float* __restrict__ dw,
                                               const float* __restrict__ db,
                                               float* __restrict__ out){
  const int t = threadIdx.x;
  float part = 0;
  for (int c = t; c < 768; c += 256)
    part += (means[c] - means[768 + c]) * (1.0f / 4096.0f) * dw[c];
  for (int off = 1; off < 64; off <<= 1) part += __shfl_xor(part, off, 64);
  __shared__ float red[4];
  if ((t & 63) == 0) red[t >> 6] = part;
  __syncthreads();
  if (t == 0){
    float r = red[0] + red[1] + red[2] + red[3] + db[0];
    out[0] = 1.0f / (1.0f + expf(-r));
  }
}

// sentinel: written when workspace is too small, to make that failure diagnosable
__global__ void sentinel_k(float* out){ out[0] = -1.0f; }

extern "C" void kernel_launch(void* const* d_in, const int* in_sizes, int n_in,
                              void* d_out, int out_size, void* d_ws, size_t ws_size,
                              hipStream_t stream){
  (void)in_sizes; (void)n_in; (void)out_size;
  const int* ids1  = (const int*)d_in[0];
  const int* ids2  = (const int*)d_in[1];
  const int* mask1 = (const int*)d_in[2];
  const int* mask2 = (const int*)d_in[3];
  const float* we = (const float*)d_in[4];
  const float* pe = (const float*)d_in[5];
  const float* eg = (const float*)d_in[6];
  const float* eb = (const float*)d_in[7];
  const float* wq = (const float*)d_in[8];
  const float* bq = (const float*)d_in[9];
  const float* wk = (const float*)d_in[10];
  const float* bk = (const float*)d_in[11];
  const float* wv = (const float*)d_in[12];
  const float* bv = (const float*)d_in[13];
  const float* wo = (const float*)d_in[14];
  const float* bo = (const float*)d_in[15];
  const float* g1 = (const float*)d_in[16];
  const float* b1 = (const float*)d_in[17];
  const float* w1 = (const float*)d_in[18];
  const float* c1 = (const float*)d_in[19];
  const float* w2 = (const float*)d_in[20];
  const float* c2 = (const float*)d_in[21];
  const float* g2 = (const float*)d_in[22];
  const float* b2 = (const float*)d_in[23];
  const float* dw = (const float*)d_in[24];
  const float* db = (const float*)d_in[25];
  float* outp = (float*)d_out;

  char* ws = (char*)d_ws;
  size_t off = 0;
  auto alloc = [&](size_t bytes) -> char* {
    char* p = ws + off;
    off += (bytes + 255) & ~(size_t)255;
    return p;
  };
  const size_t W768 = (size_t)768 * 768;
  const size_t WFF  = (size_t)768 * 3072;
  unsigned short* wqkvT = (unsigned short*)alloc(3 * NL * W768 * 2);
  unsigned short* woT   = (unsigned short*)alloc(NL * W768 * 2);
  unsigned short* w1T   = (unsigned short*)alloc(NL * WFF * 2);
  unsigned short* w2T   = (unsigned short*)alloc(NL * WFF * 2);
  unsigned short* xb    = (unsigned short*)alloc((size_t)8192 * 768 * 2);
  unsigned short* qb_   = (unsigned short*)alloc((size_t)8192 * 768 * 2);
  unsigned short* kb_   = (unsigned short*)alloc((size_t)8192 * 768 * 2);
  unsigned short* vb_   = (unsigned short*)alloc((size_t)8192 * 768 * 2);
  unsigned short* hb    = (unsigned short*)alloc((size_t)8192 * 3072 * 2);
  unsigned short* vt    = (unsigned short*)alloc((size_t)2 * 768 * 4096 * 2);
  float* means          = (float*)alloc(2 * 768 * 4);
  if (off > ws_size){ sentinel_k<<<1, 1, 0, stream>>>(outp); return; }

  // one-time (per call) weight convert+transpose to bf16 B^T layout
  transpose_cvt<<<dim3(12, 12, NL), 256, 0, stream>>>(wq, wqkvT,                 768, 768);
  transpose_cvt<<<dim3(12, 12, NL), 256, 0, stream>>>(wk, wqkvT + NL * W768,     768, 768);
  transpose_cvt<<<dim3(12, 12, NL), 256, 0, stream>>>(wv, wqkvT + 2 * NL * W768, 768, 768);
  transpose_cvt<<<dim3(12, 12, NL), 256, 0, stream>>>(wo, woT,                   768, 768);
  transpose_cvt<<<dim3(48, 12, NL), 256, 0, stream>>>(w1, w1T,                   768, 3072);
  transpose_cvt<<<dim3(12, 48, NL), 256, 0, stream>>>(w2, w2T,                   3072, 768);

  embed_ln<<<8192, 192, 0, stream>>>(ids1, ids2, we, pe, eg, eb, xb);

  for (int l = 0; l < NL; l++){
    qkv_gemm<<<dim3(64, 18), 256, 0, stream>>>(xb, wqkvT, l, bq + l * 768, bk + l * 768, bv + l * 768,
                                               qb_, kb_, vb_);
    transpose64<<<dim3(12, 64, 2), 256, 0, stream>>>(vb_, vt, 4096, 768);
    attn_kernel<<<dim3(64, 12, 2), 256, 0, stream>>>(qb_, kb_, vt, mask1, mask2, vb_);
    gemm_bt<0><<<dim3(64, 6), 256, 0, stream>>>(vb_, woT + (size_t)l * W768, bo + l * 768, qb_, 768, 768);
    add_ln<<<8192, 192, 0, stream>>>(xb, qb_, g1 + l * 768, b1 + l * 768, kb_);
    gemm_bt<1><<<dim3(64, 24), 256, 0, stream>>>(kb_, w1T + (size_t)l * WFF, c1 + l * 3072, hb, 3072, 768);
    gemm_bt<0><<<dim3(64, 6), 256, 0, stream>>>(hb, w2T + (size_t)l * WFF, c2 + l * 768, vb_, 768, 3072);
    add_ln<<<8192, 192, 0, stream>>>(kb_, vb_, g2 + l * 768, b2 + l * 768, xb);
  }

  hipMemsetAsync(means, 0, 2 * 768 * 4, stream);
  colmean<<<dim3(64, 2), 256, 0, stream>>>(xb, means);
  final_k<<<1, 256, 0, stream>>>(means, dw, db, outp);
}